// Round 3
// baseline (465.703 us; speedup 1.0000x reference)
//
#include <hip/hip_runtime.h>
#include <math.h>

#define BB 32
#define NN 128
#define CC 16
#define OO 32
#define II 32
#define JJ 32
#define MM (NN*CC)

// One block per (b,o); the whole 3-iteration routing is independent per (b,o)
// (softmax is over the m=2048 axis, not over o). x[b] and W[:,o,nn,:] live in
// registers; b_ij row values live in registers (same thread produces and
// consumes its 4 (c,n) entries); only ~6 KB LDS for cross-thread reductions.
__global__ __launch_bounds__(512, 2) void k_caps(
    const float* __restrict__ x, const float* __restrict__ W,
    float* __restrict__ out) {
  __shared__ __align__(16) float cxo[512];      // cx[c,i] for this (b,o)
  __shared__ __align__(16) float wvs[512];      // wv[c,i] = sum_j W*v
  __shared__ __align__(16) float swred[8 * 32]; // per-wave s[j] partials
  __shared__ __align__(16) float vj[32];        // squashed capsule
  __shared__ float red1[8];
  __shared__ float red2[8];

  int bid = blockIdx.x;
  int b = ((bid & 7) << 2) | ((bid >> 3) & 3);  // XCD-affinity: same-b -> same XCD L2
  int o = bid >> 5;
  int tid = threadIdx.x;
  int c = tid >> 5, nn = tid & 31;
  int lane = tid & 63, wave = tid >> 6;

  // x[b, n, c, 0:31] for n = nn + 32*jn -> 128 VGPRs (each 128B line owned by one thread)
  float4 xr4[4][8];
  {
    const float* xp = x + (size_t)b * (NN * CC * II) + nn * (CC * II) + c * II;
    #pragma unroll
    for (int jn = 0; jn < 4; ++jn) {
      const float* pj = xp + jn * (32 * CC * II);
      #pragma unroll
      for (int q = 0; q < 8; ++q) xr4[jn][q] = *(const float4*)(pj + 4 * q);
    }
  }
  // W[c, o, i=nn, 0:31] -> 32 VGPRs
  float4 Wr4[8];
  {
    const float* wp = W + ((size_t)(c * OO + o) * II + nn) * JJ;
    #pragma unroll
    for (int q = 0; q < 8; ++q) Wr4[q] = *(const float4*)(wp + 4 * q);
  }

  float bv[4] = {0.f, 0.f, 0.f, 0.f};  // my 4 b_ij entries (c, n=nn+32*jn)
  float mx = 0.f;
  float rinv = 1.0f / (float)MM;       // t=0: softmax(0) == uniform 1/2048

  for (int t = 0; t < 3; ++t) {
    // ---- phase A: p[i] = sum over my 4 n of coef[c,n]*x[n,c,i]
    float p[32];
    #pragma unroll
    for (int i = 0; i < 32; ++i) p[i] = 0.f;
    #pragma unroll
    for (int jn = 0; jn < 4; ++jn) {
      float cf = __expf(bv[jn] - mx) * rinv;
      #pragma unroll
      for (int q = 0; q < 8; ++q) {
        p[4*q+0] = fmaf(cf, xr4[jn][q].x, p[4*q+0]);
        p[4*q+1] = fmaf(cf, xr4[jn][q].y, p[4*q+1]);
        p[4*q+2] = fmaf(cf, xr4[jn][q].z, p[4*q+2]);
        p[4*q+3] = fmaf(cf, xr4[jn][q].w, p[4*q+3]);
      }
    }
    // vector-halving butterfly over the 32 lanes sharing c:
    // lane nn ends holding cxo[c][nn] (element id = sum of kept-half bits = nn)
    #pragma unroll
    for (int h = 16; h >= 1; h >>= 1) {
      bool hi = (nn & h) != 0;
      #pragma unroll
      for (int e = 0; e < 16; ++e) {
        if (e < h) {
          float send = hi ? p[e] : p[e + h];
          float keep = hi ? p[e + h] : p[e];
          float recv = __shfl_xor(send, h);
          p[e] = keep + recv;
        }
      }
    }
    cxo[tid] = p[0];
    __syncthreads();

    // ---- s[j] = sum_{c,i} cxo[c,i] * W[c,o,i,j]
    float cc = cxo[tid];
    float sp[32];
    #pragma unroll
    for (int q = 0; q < 8; ++q) {
      sp[4*q+0] = cc * Wr4[q].x;
      sp[4*q+1] = cc * Wr4[q].y;
      sp[4*q+2] = cc * Wr4[q].z;
      sp[4*q+3] = cc * Wr4[q].w;
    }
    #pragma unroll
    for (int h = 16; h >= 1; h >>= 1) {
      bool hi = (nn & h) != 0;
      #pragma unroll
      for (int e = 0; e < 16; ++e) {
        if (e < h) {
          float send = hi ? sp[e] : sp[e + h];
          float keep = hi ? sp[e + h] : sp[e];
          float recv = __shfl_xor(send, h);
          sp[e] = keep + recv;
        }
      }
    }
    float sv = sp[0] + __shfl_xor(sp[0], 32);   // fold this wave's two c's
    if (lane < 32) swred[wave * 32 + lane] = sv;
    __syncthreads();

    // ---- squash on 32 threads
    if (tid < 32) {
      float s = 0.f;
      #pragma unroll
      for (int w = 0; w < 8; ++w) s += swred[w * 32 + tid];
      float msq = s * s;
      #pragma unroll
      for (int off = 16; off > 0; off >>= 1) msq += __shfl_xor(msq, off);
      float mag = sqrtf(msq) + 1e-11f;
      float a = msq / (1.0f + msq);
      float vv = a * s / mag;
      vj[tid] = vv;
      if (t == 2) {
        out[((size_t)b * OO + o) * JJ + tid] = vv;       // v_j [B,1,O,J]
        if (tid == 0) out[BB * OO * JJ + b * OO + o] = a; // a_j [B,1,O,1]
      }
    }
    __syncthreads();
    if (t == 2) break;   // reference discards the last b_ij update

    // ---- wv[c,i] = sum_j W[c,o,i,j] * v[j]
    {
      float acc = 0.f;
      #pragma unroll
      for (int q = 0; q < 8; ++q) {
        float4 v4 = *(const float4*)&vj[4 * q];
        acc = fmaf(Wr4[q].x, v4.x, acc);
        acc = fmaf(Wr4[q].y, v4.y, acc);
        acc = fmaf(Wr4[q].z, v4.z, acc);
        acc = fmaf(Wr4[q].w, v4.w, acc);
      }
      wvs[tid] = acc;
    }
    __syncthreads();

    // ---- phase B: bv[jn] += sum_i x[n,c,i]*wv[c,i]; then block softmax stats
    float m4 = -3.0e38f;
    #pragma unroll
    for (int jn = 0; jn < 4; ++jn) {
      float acc = 0.f;
      #pragma unroll
      for (int q = 0; q < 8; ++q) {
        float4 w4 = *(const float4*)&wvs[c * 32 + 4 * q];  // broadcast per c-group
        acc = fmaf(xr4[jn][q].x, w4.x, acc);
        acc = fmaf(xr4[jn][q].y, w4.y, acc);
        acc = fmaf(xr4[jn][q].z, w4.z, acc);
        acc = fmaf(xr4[jn][q].w, w4.w, acc);
      }
      bv[jn] += acc;
      m4 = fmaxf(m4, bv[jn]);
    }
    #pragma unroll
    for (int off = 32; off > 0; off >>= 1) m4 = fmaxf(m4, __shfl_xor(m4, off));
    if (lane == 0) red1[wave] = m4;
    __syncthreads();
    mx = fmaxf(fmaxf(fmaxf(red1[0], red1[1]), fmaxf(red1[2], red1[3])),
               fmaxf(fmaxf(red1[4], red1[5]), fmaxf(red1[6], red1[7])));
    float s4 = 0.f;
    #pragma unroll
    for (int k = 0; k < 4; ++k) s4 += __expf(bv[k] - mx);
    #pragma unroll
    for (int off = 32; off > 0; off >>= 1) s4 += __shfl_xor(s4, off);
    if (lane == 0) red2[wave] = s4;
    __syncthreads();
    rinv = 1.0f / (((red2[0] + red2[1]) + (red2[2] + red2[3])) +
                   ((red2[4] + red2[5]) + (red2[6] + red2[7])));
  }
}

extern "C" void kernel_launch(void* const* d_in, const int* in_sizes, int n_in,
                              void* d_out, int out_size, void* d_ws, size_t ws_size,
                              hipStream_t stream) {
  const float* x = (const float*)d_in[0];   // [B,N,C,I] fp32
  const float* W = (const float*)d_in[1];   // [C,O,I,J] fp32
  (void)in_sizes; (void)n_in; (void)d_ws; (void)ws_size; (void)out_size;
  float* out = (float*)d_out;               // v_j (32768) ++ a_j (1024)
  k_caps<<<BB * OO, 512, 0, stream>>>(x, W, out);
}

// Round 4
// 412.237 us; speedup vs baseline: 1.1297x; 1.1297x over previous
//
#include <hip/hip_runtime.h>
#include <math.h>

#define BB 32
#define NN 128
#define CC 16
#define OO 32
#define II 32
#define JJ 32
#define MM (NN*CC)

// One block per (b,o), 1024 threads. Thread t owns u_hat rows m0=(c0=t>>7, n=t&127)
// and m1=(c0+8, n) IN REGISTERS (u0[32], u1[32]). Setup computes them once
// (fp32 VALU GEMM, 2048 MAC/thread); the 3 routing iterations then never touch
// x or W again: s-phase and u.v are register math + shuffle butterflies.
// b_ij lives in bv[2] registers (m-order (c,n) is a permutation of the
// reference's (n,c) — softmax/sums over m are permutation-invariant).
// Live VGPRs ~116 (< 128 cap) — R3's spill came from a ~210-reg plan.
__global__ __launch_bounds__(1024, 4) void k_caps(
    const float* __restrict__ x, const float* __restrict__ W,
    float* __restrict__ out) {
  __shared__ float swred[16][32];   // per-wave s[j] partials
  __shared__ float vj[32];          // squashed capsule
  __shared__ float red1[16], red2[16];

  int bid = blockIdx.x;
  int b = ((bid & 7) << 2) | ((bid >> 3) & 3);  // XCD-affinity: same-b -> same XCD L2
  int o = bid >> 5;
  int tid = threadIdx.x;
  int lane = tid & 63, wave = tid >> 6;
  int nn = tid & 31;

  int n  = tid & 127;
  int c0 = tid >> 7;          // 0..7 (wave-uniform)
  int c1 = c0 + 8;

  // ---- setup: u0[j] = sum_i x[b,n,c0,i]*W[c0,o,i,j]; u1 likewise (c1) ----
  float u0[32], u1[32];
  #pragma unroll
  for (int j = 0; j < 32; ++j) { u0[j] = 0.f; u1[j] = 0.f; }

  {
    const float* xp0 = x + ((size_t)(b * NN + n) * CC + c0) * II;
    const float* wp0 = W + ((size_t)(c0 * OO + o) * II) * JJ;
    #pragma unroll
    for (int q = 0; q < 8; ++q) {
      float4 x4 = *(const float4*)(xp0 + 4 * q);   // lane-contiguous row; L1 reuses lines
      #pragma unroll
      for (int r = 0; r < 4; ++r) {
        float xi = (r == 0) ? x4.x : (r == 1) ? x4.y : (r == 2) ? x4.z : x4.w;
        const float* wrow = wp0 + (size_t)(4 * q + r) * JJ;  // wave-uniform addr -> L1 broadcast
        #pragma unroll
        for (int jq = 0; jq < 8; ++jq) {
          float4 w4 = *(const float4*)(wrow + 4 * jq);
          u0[4*jq+0] = fmaf(xi, w4.x, u0[4*jq+0]);
          u0[4*jq+1] = fmaf(xi, w4.y, u0[4*jq+1]);
          u0[4*jq+2] = fmaf(xi, w4.z, u0[4*jq+2]);
          u0[4*jq+3] = fmaf(xi, w4.w, u0[4*jq+3]);
        }
      }
    }
  }
  {
    const float* xp1 = x + ((size_t)(b * NN + n) * CC + c1) * II;
    const float* wp1 = W + ((size_t)(c1 * OO + o) * II) * JJ;
    #pragma unroll
    for (int q = 0; q < 8; ++q) {
      float4 x4 = *(const float4*)(xp1 + 4 * q);
      #pragma unroll
      for (int r = 0; r < 4; ++r) {
        float xi = (r == 0) ? x4.x : (r == 1) ? x4.y : (r == 2) ? x4.z : x4.w;
        const float* wrow = wp1 + (size_t)(4 * q + r) * JJ;
        #pragma unroll
        for (int jq = 0; jq < 8; ++jq) {
          float4 w4 = *(const float4*)(wrow + 4 * jq);
          u1[4*jq+0] = fmaf(xi, w4.x, u1[4*jq+0]);
          u1[4*jq+1] = fmaf(xi, w4.y, u1[4*jq+1]);
          u1[4*jq+2] = fmaf(xi, w4.z, u1[4*jq+2]);
          u1[4*jq+3] = fmaf(xi, w4.w, u1[4*jq+3]);
        }
      }
    }
  }

  // ---- 3 routing iterations, all register/LDS-local ----
  float bv0 = 0.f, bv1 = 0.f;          // my two b_ij entries
  float mx = 0.f;
  float rinv = 1.0f / (float)MM;       // softmax(0) == uniform 1/2048

  for (int t = 0; t < 3; ++t) {
    // s[j] partials = cf0*u0[j] + cf1*u1[j]
    float cf0 = __expf(bv0 - mx) * rinv;
    float cf1 = __expf(bv1 - mx) * rinv;
    float sp[32];
    #pragma unroll
    for (int j = 0; j < 32; ++j) sp[j] = fmaf(cf0, u0[j], cf1 * u1[j]);

    // vector-halving butterfly over the 32-lane halves (lane nn ends with elem nn)
    #pragma unroll
    for (int h = 16; h >= 1; h >>= 1) {
      bool hi = (nn & h) != 0;
      #pragma unroll
      for (int e = 0; e < 16; ++e) {
        if (e < h) {
          float send = hi ? sp[e] : sp[e + h];
          float keep = hi ? sp[e + h] : sp[e];
          float recv = __shfl_xor(send, h);
          sp[e] = keep + recv;
        }
      }
    }
    float sv = sp[0] + __shfl_xor(sp[0], 32);   // fold the wave's two halves
    if (lane < 32) swred[wave][lane] = sv;
    __syncthreads();

    // squash on 32 threads
    if (tid < 32) {
      float s = 0.f;
      #pragma unroll
      for (int w = 0; w < 16; ++w) s += swred[w][tid];
      float msq = s * s;
      #pragma unroll
      for (int off = 16; off > 0; off >>= 1) msq += __shfl_xor(msq, off);
      float mag = sqrtf(msq) + 1e-11f;
      float a = msq / (1.0f + msq);
      float vv = a * s / mag;
      vj[tid] = vv;
      if (t == 2) {
        out[((size_t)b * OO + o) * JJ + tid] = vv;        // v_j [B,1,O,J]
        if (tid == 0) out[BB * OO * JJ + b * OO + o] = a; // a_j [B,1,O,1]
      }
    }
    __syncthreads();
    if (t == 2) break;   // reference discards the last b_ij update

    // u.v per row (register dot with vj), update b_ij, block softmax stats
    float vr0 = 0.f, vr1 = 0.f, vr2 = 0.f, vr3 = 0.f;
    float wr0 = 0.f, wr1 = 0.f, wr2 = 0.f, wr3 = 0.f;
    #pragma unroll
    for (int q = 0; q < 8; ++q) {
      float4 v4 = *(const float4*)&vj[4 * q];   // broadcast LDS read
      vr0 = fmaf(u0[4*q+0], v4.x, vr0);
      vr1 = fmaf(u0[4*q+1], v4.y, vr1);
      vr2 = fmaf(u0[4*q+2], v4.z, vr2);
      vr3 = fmaf(u0[4*q+3], v4.w, vr3);
      wr0 = fmaf(u1[4*q+0], v4.x, wr0);
      wr1 = fmaf(u1[4*q+1], v4.y, wr1);
      wr2 = fmaf(u1[4*q+2], v4.z, wr2);
      wr3 = fmaf(u1[4*q+3], v4.w, wr3);
    }
    bv0 += (vr0 + vr1) + (vr2 + vr3);
    bv1 += (wr0 + wr1) + (wr2 + wr3);

    float m_ = fmaxf(bv0, bv1);
    #pragma unroll
    for (int off = 32; off > 0; off >>= 1) m_ = fmaxf(m_, __shfl_xor(m_, off));
    if (lane == 0) red1[wave] = m_;
    __syncthreads();
    mx = red1[0];
    #pragma unroll
    for (int w = 1; w < 16; ++w) mx = fmaxf(mx, red1[w]);

    float sx = __expf(bv0 - mx) + __expf(bv1 - mx);
    #pragma unroll
    for (int off = 32; off > 0; off >>= 1) sx += __shfl_xor(sx, off);
    if (lane == 0) red2[wave] = sx;
    __syncthreads();
    float rs = red2[0];
    #pragma unroll
    for (int w = 1; w < 16; ++w) rs += red2[w];
    rinv = 1.0f / rs;
    __syncthreads();   // protect red1/red2/swred reuse next iteration
  }
}

extern "C" void kernel_launch(void* const* d_in, const int* in_sizes, int n_in,
                              void* d_out, int out_size, void* d_ws, size_t ws_size,
                              hipStream_t stream) {
  const float* x = (const float*)d_in[0];   // [B,N,C,I] fp32
  const float* W = (const float*)d_in[1];   // [C,O,I,J] fp32
  (void)in_sizes; (void)n_in; (void)d_ws; (void)ws_size; (void)out_size;
  float* out = (float*)d_out;               // v_j (32768) ++ a_j (1024)
  k_caps<<<BB * OO, 1024, 0, stream>>>(x, W, out);
}

// Round 5
// 393.069 us; speedup vs baseline: 1.1848x; 1.0488x over previous
//
#include <hip/hip_runtime.h>
#include <math.h>

#define BB 32
#define NN 128
#define CC 16
#define OO 32
#define II 32
#define JJ 32
#define MM (NN*CC)

// One block per (b,o), 1024 threads. Thread t owns u_hat rows m0=(c0=t>>7, n=t&127)
// and m1=(c0+8, n) in registers (u0[32], u1[32] = 64 VGPRs). Setup computes them
// once (fp32 VALU GEMM, 2048 FMA/thread); the 3 routing iterations are register
// math + shuffle butterflies + ~2.5 KB LDS. b_ij lives in bv0/bv1 registers
// (m-order (c,n) is a permutation of the reference's (n,c); softmax over m is
// permutation-invariant).
//
// amdgpu_waves_per_eu(4,4): R4 proved launch_bounds' 2nd arg is only a MINIMUM
// waves/EU — the allocator chose 8 waves/EU (64 VGPRs) and spilled 321 MB to
// scratch. Pinning min=max=4 gives the full 128-VGPR budget (peak live ~100).
__global__
__attribute__((amdgpu_flat_work_group_size(1024, 1024)))
__attribute__((amdgpu_waves_per_eu(4, 4)))
void k_caps(const float* __restrict__ x, const float* __restrict__ W,
            float* __restrict__ out) {
  __shared__ float swred[16][32];   // per-wave s[j] partials
  __shared__ float vj[32];          // squashed capsule
  __shared__ float red1[16], red2[16];

  int bid = blockIdx.x;
  int b = ((bid & 7) << 2) | ((bid >> 3) & 3);  // XCD-affinity: same-b -> same XCD L2
  int o = bid >> 5;
  int tid = threadIdx.x;
  int lane = tid & 63, wave = tid >> 6;
  int nn = tid & 31;

  int n  = tid & 127;
  int c0 = tid >> 7;          // 0..7 (wave-uniform)
  int c1 = c0 + 8;

  // ---- setup: u0[j] = sum_i x[b,n,c0,i]*W[c0,o,i,j]; u1 likewise (c1) ----
  float u0[32], u1[32];
  #pragma unroll
  for (int j = 0; j < 32; ++j) { u0[j] = 0.f; u1[j] = 0.f; }

  {
    const float* xp0 = x + ((size_t)(b * NN + n) * CC + c0) * II;
    const float* wp0 = W + ((size_t)(c0 * OO + o) * II) * JJ;
    #pragma unroll
    for (int q = 0; q < 8; ++q) {
      float4 x4 = *(const float4*)(xp0 + 4 * q);   // lane-private 128B row, L1-resident
      #pragma unroll
      for (int r = 0; r < 4; ++r) {
        float xi = (r == 0) ? x4.x : (r == 1) ? x4.y : (r == 2) ? x4.z : x4.w;
        const float* wrow = wp0 + (size_t)(4 * q + r) * JJ;  // wave-uniform -> L1 broadcast
        #pragma unroll
        for (int jq = 0; jq < 8; ++jq) {
          float4 w4 = *(const float4*)(wrow + 4 * jq);
          u0[4*jq+0] = fmaf(xi, w4.x, u0[4*jq+0]);
          u0[4*jq+1] = fmaf(xi, w4.y, u0[4*jq+1]);
          u0[4*jq+2] = fmaf(xi, w4.z, u0[4*jq+2]);
          u0[4*jq+3] = fmaf(xi, w4.w, u0[4*jq+3]);
        }
      }
    }
  }
  {
    const float* xp1 = x + ((size_t)(b * NN + n) * CC + c1) * II;
    const float* wp1 = W + ((size_t)(c1 * OO + o) * II) * JJ;
    #pragma unroll
    for (int q = 0; q < 8; ++q) {
      float4 x4 = *(const float4*)(xp1 + 4 * q);
      #pragma unroll
      for (int r = 0; r < 4; ++r) {
        float xi = (r == 0) ? x4.x : (r == 1) ? x4.y : (r == 2) ? x4.z : x4.w;
        const float* wrow = wp1 + (size_t)(4 * q + r) * JJ;
        #pragma unroll
        for (int jq = 0; jq < 8; ++jq) {
          float4 w4 = *(const float4*)(wrow + 4 * jq);
          u1[4*jq+0] = fmaf(xi, w4.x, u1[4*jq+0]);
          u1[4*jq+1] = fmaf(xi, w4.y, u1[4*jq+1]);
          u1[4*jq+2] = fmaf(xi, w4.z, u1[4*jq+2]);
          u1[4*jq+3] = fmaf(xi, w4.w, u1[4*jq+3]);
        }
      }
    }
  }

  // ---- 3 routing iterations, all register/LDS-local ----
  float bv0 = 0.f, bv1 = 0.f;          // my two b_ij entries
  float mx = 0.f;
  float rinv = 1.0f / (float)MM;       // softmax(0) == uniform 1/2048

  for (int t = 0; t < 3; ++t) {
    float cf0 = __expf(bv0 - mx) * rinv;
    float cf1 = __expf(bv1 - mx) * rinv;

    // s[j] partials: fuse construction with the h=16 butterfly stage so only
    // 16 temps stay live (peak-register shaving vs R4's sp[32]).
    float sp[16];
    {
      bool hi16 = (nn & 16) != 0;
      #pragma unroll
      for (int e = 0; e < 16; ++e) {
        float a  = fmaf(cf0, u0[e],      cf1 * u1[e]);
        float bq = fmaf(cf0, u0[e + 16], cf1 * u1[e + 16]);
        float send = hi16 ? a : bq;
        float keep = hi16 ? bq : a;
        sp[e] = keep + __shfl_xor(send, 16);
      }
    }
    // remaining butterfly stages: lane nn ends holding element nn
    #pragma unroll
    for (int h = 8; h >= 1; h >>= 1) {
      bool hi = (nn & h) != 0;
      #pragma unroll
      for (int e = 0; e < 8; ++e) {
        if (e < h) {
          float send = hi ? sp[e] : sp[e + h];
          float keep = hi ? sp[e + h] : sp[e];
          sp[e] = keep + __shfl_xor(send, h);
        }
      }
    }
    float sv = sp[0] + __shfl_xor(sp[0], 32);   // fold the wave's two halves
    if (lane < 32) swred[wave][lane] = sv;
    __syncthreads();

    // squash on 32 threads
    if (tid < 32) {
      float s = 0.f;
      #pragma unroll
      for (int w = 0; w < 16; ++w) s += swred[w][tid];
      float msq = s * s;
      #pragma unroll
      for (int off = 16; off > 0; off >>= 1) msq += __shfl_xor(msq, off);
      float mag = sqrtf(msq) + 1e-11f;
      float a = msq / (1.0f + msq);
      float vv = a * s / mag;
      vj[tid] = vv;
      if (t == 2) {
        out[((size_t)b * OO + o) * JJ + tid] = vv;        // v_j [B,1,O,J]
        if (tid == 0) out[BB * OO * JJ + b * OO + o] = a; // a_j [B,1,O,1]
      }
    }
    __syncthreads();
    if (t == 2) break;   // reference discards the last b_ij update

    // u.v per row (register dot with vj), update b_ij, block softmax stats
    float vr0 = 0.f, vr1 = 0.f, vr2 = 0.f, vr3 = 0.f;
    float wr0 = 0.f, wr1 = 0.f, wr2 = 0.f, wr3 = 0.f;
    #pragma unroll
    for (int q = 0; q < 8; ++q) {
      float4 v4 = *(const float4*)&vj[4 * q];   // broadcast LDS read
      vr0 = fmaf(u0[4*q+0], v4.x, vr0);
      vr1 = fmaf(u0[4*q+1], v4.y, vr1);
      vr2 = fmaf(u0[4*q+2], v4.z, vr2);
      vr3 = fmaf(u0[4*q+3], v4.w, vr3);
      wr0 = fmaf(u1[4*q+0], v4.x, wr0);
      wr1 = fmaf(u1[4*q+1], v4.y, wr1);
      wr2 = fmaf(u1[4*q+2], v4.z, wr2);
      wr3 = fmaf(u1[4*q+3], v4.w, wr3);
    }
    bv0 += (vr0 + vr1) + (vr2 + vr3);
    bv1 += (wr0 + wr1) + (wr2 + wr3);

    float m_ = fmaxf(bv0, bv1);
    #pragma unroll
    for (int off = 32; off > 0; off >>= 1) m_ = fmaxf(m_, __shfl_xor(m_, off));
    if (lane == 0) red1[wave] = m_;
    __syncthreads();
    mx = red1[0];
    #pragma unroll
    for (int w = 1; w < 16; ++w) mx = fmaxf(mx, red1[w]);

    float sx = __expf(bv0 - mx) + __expf(bv1 - mx);
    #pragma unroll
    for (int off = 32; off > 0; off >>= 1) sx += __shfl_xor(sx, off);
    if (lane == 0) red2[wave] = sx;
    __syncthreads();
    float rs = red2[0];
    #pragma unroll
    for (int w = 1; w < 16; ++w) rs += red2[w];
    rinv = 1.0f / rs;
    __syncthreads();   // protect red1/red2/swred reuse next iteration
  }
}

extern "C" void kernel_launch(void* const* d_in, const int* in_sizes, int n_in,
                              void* d_out, int out_size, void* d_ws, size_t ws_size,
                              hipStream_t stream) {
  const float* x = (const float*)d_in[0];   // [B,N,C,I] fp32
  const float* W = (const float*)d_in[1];   // [C,O,I,J] fp32
  (void)in_sizes; (void)n_in; (void)d_ws; (void)ws_size; (void)out_size;
  float* out = (float*)d_out;               // v_j (32768) ++ a_j (1024)
  k_caps<<<BB * OO, 1024, 0, stream>>>(x, W, out);
}